// Round 5
// baseline (628.413 us; speedup 1.0000x reference)
//
#include <hip/hip_runtime.h>
#include <hip/hip_fp16.h>
#include <stdint.h>

#define CBP_D 8192
#define CBP_C 512
#define CBP_W 512
#define ROWS 64          // rows staged per block; lane covers 4 rows
#define NTHREADS 1024    // 16 waves
#define NSPLIT 4         // 64 row-blocks x 4 = 256 blocks = 1/CU
#define NCAP 72          // fixed pair-list capacity per d (mean 32, +7 sigma)

// LDS layout (bytes): x2 rows 0..512 (513*128, row 512 = zeros), then x1 rows 0..511
#define X1OFF 65664
#define PADW  (512u << 17)   // pad pair word: j=512 (zero row), i=0

// ================= precompute =================

// pA: single block. cnt2 (histogram of h2), boff (exclusive scan), bucket2
// (j's grouped by target bucket, deterministic order via rank).
__global__ void pA_buckets(const int* __restrict__ h2, int* __restrict__ cnt2_g,
                           int* __restrict__ boff_g, int* __restrict__ bucket2_g) {
    __shared__ int scnt[CBP_D];
    __shared__ int sh2[CBP_C];
    __shared__ int ssum[512];
    int t = threadIdx.x;            // 512 threads
    for (int k = t; k < CBP_D; k += 512) scnt[k] = 0;
    sh2[t] = h2[t];
    __syncthreads();
    atomicAdd(&scnt[sh2[t]], 1);    // counts order-independent -> deterministic
    __syncthreads();
    int base = t * 16;
    int loc[16]; int s = 0;
#pragma unroll
    for (int k = 0; k < 16; ++k) { loc[k] = scnt[base + k]; cnt2_g[base + k] = loc[k]; s += loc[k]; }
    ssum[t] = s;
    __syncthreads();
    int acc = s;
    for (int off = 1; off < 512; off <<= 1) {
        int add = (t >= off) ? ssum[t - off] : 0;
        __syncthreads();
        acc += add; ssum[t] = acc;
        __syncthreads();
    }
    int excl = acc - s;
#pragma unroll
    for (int k = 0; k < 16; ++k) { boff_g[base + k] = excl; scnt[base + k] = excl; excl += loc[k]; }
    __syncthreads();
    int h = sh2[t]; int r = 0;
    for (int j2 = 0; j2 < t; ++j2) r += (sh2[j2] == h);
    bucket2_g[scnt[h] + r] = t;
}

// pB: per-d pair lists at fixed stride NCAP, padded to multiple of 4 with PADW;
// actual (padded) count in cnt[d]. Deterministic i-major, bucket-order j.
__global__ void pB_fill(const int* __restrict__ h1, const int* __restrict__ cnt2,
                        const int* __restrict__ boff, const int* __restrict__ bucket2,
                        int* __restrict__ cnt, uint32_t* __restrict__ pairs) {
    __shared__ int sc[CBP_D];       // 32 KB
    __shared__ int sb[CBP_D];       // 32 KB
    __shared__ short sbk[CBP_C];
    __shared__ int sh1[CBP_C];
    int tid = threadIdx.x;          // 128
    for (int k = tid; k < CBP_D; k += 128) { sc[k] = cnt2[k]; sb[k] = boff[k]; }
    for (int k = tid; k < CBP_C; k += 128) { sbk[k] = (short)bucket2[k]; sh1[k] = h1[k]; }
    __syncthreads();
    int d = blockIdx.x * 128 + tid;
    uint32_t* pd = pairs + (size_t)d * NCAP;
    int pos = 0;
    for (int i = 0; i < CBP_C; ++i) {
        int t = (d - sh1[i]) & (CBP_D - 1);
        int n = sc[t];
        if (n) {
            int bo = sb[t];
            uint32_t iw = (uint32_t)(i << 7);
            for (int k = 0; k < n && pos < NCAP; ++k)
                pd[pos++] = iw | ((uint32_t)sbk[bo + k] << 17);
        }
    }
    while (pos & 3) pd[pos++] = PADW;
    cnt[d] = pos;
}

// ================= main =================

// All 64 lanes work on ONE d; group g (lane>>4) takes entry slot t4*4+g.
// Lane l (lane&15) covers rows 4l..4l+3 via one ds_read_b64 per operand.
#define PROC(P) { \
    uint32_t p_ = (P); \
    uint32_t aB_ = (p_ & 0x1FF80u) + baseA; \
    uint32_t bB_ = ((p_ >> 10) & 0x1FF80u) | baseB; \
    uint2 ra_ = *(const uint2*)(xsh + aB_); \
    uint2 rb_ = *(const uint2*)(xsh + bB_); \
    acc01 = __hfma2(*(const __half2*)&ra_.x, *(const __half2*)&rb_.x, acc01); \
    acc23 = __hfma2(*(const __half2*)&ra_.y, *(const __half2*)&rb_.y, acc23); }

__global__ __launch_bounds__(NTHREADS, 1)
void k_main(const float* __restrict__ b1, const float* __restrict__ b2,
            const float* __restrict__ s1, const float* __restrict__ s2,
            const int* __restrict__ cnt, const uint32_t* __restrict__ pairs,
            float* __restrict__ out) {
    __shared__ __align__(16) char xsh[131200];   // x2 (513 rows incl zero) + x1 (512)
    int bx = blockIdx.x;                   // 0..63 row-block
    int gy = blockIdx.y;                   // 0..3
    int r_base = bx * ROWS;
    int b = r_base >> 9;
    int w0 = r_base & (CBP_W - 1);
    int tid = threadIdx.x;

    // stage sign-folded f16, transposed [c][r]; x2 at 0, x1 at X1OFF
    for (int u = tid; u < CBP_C * 8; u += NTHREADS) {
        int c = u >> 3;
        int r8 = (u & 7) << 3;
        size_t g = ((size_t)(b * CBP_C + c)) * CBP_W + w0 + r8;
        float4 u0 = *(const float4*)(b1 + g), u1 = *(const float4*)(b1 + g + 4);
        float4 v0 = *(const float4*)(b2 + g), v1 = *(const float4*)(b2 + g + 4);
        float sa = s1[c], sb = s2[c];
        union { __half2 h2[4]; uint4 q; } A, Bv;
        A.h2[0] = __floats2half2_rn(u0.x * sa, u0.y * sa);
        A.h2[1] = __floats2half2_rn(u0.z * sa, u0.w * sa);
        A.h2[2] = __floats2half2_rn(u1.x * sa, u1.y * sa);
        A.h2[3] = __floats2half2_rn(u1.z * sa, u1.w * sa);
        Bv.h2[0] = __floats2half2_rn(v0.x * sb, v0.y * sb);
        Bv.h2[1] = __floats2half2_rn(v0.z * sb, v0.w * sb);
        Bv.h2[2] = __floats2half2_rn(v1.x * sb, v1.y * sb);
        Bv.h2[3] = __floats2half2_rn(v1.z * sb, v1.w * sb);
        *(uint4*)(xsh + X1OFF + (c << 7) + (r8 << 1)) = A.q;
        *(uint4*)(xsh + (c << 7) + (r8 << 1)) = Bv.q;
    }
    if (tid < 8) *(uint4*)(xsh + 65536 + tid * 16) = make_uint4(0, 0, 0, 0);
    __syncthreads();

    int wv = tid >> 6;                     // 0..15
    int lane = tid & 63;
    int g4 = lane >> 4;                    // entry-slot group 0..3
    int l = lane & 15;                     // rows 4l..4l+3
    uint32_t baseA = (uint32_t)(X1OFF + (l << 3));
    uint32_t baseB = (uint32_t)(l << 3);
    int dbase = gy * (CBP_D / NSPLIT) + wv * 128;   // wave owns 128 contiguous d's
    // lane stores row 4l + g4 after cross-group reduce
    float* orow = out + (size_t)(r_base + (l << 2) + g4) * CBP_D;

    for (int dd = 0; dd < 128; ++dd) {
        int d = dbase + dd;
        int n4 = __builtin_amdgcn_readfirstlane(cnt[d]);   // uniform, mult of 4
        const uint32_t* pl = pairs + (size_t)d * NCAP + g4;
        __half2 acc01 = __float2half2_rn(0.f);
        __half2 acc23 = __float2half2_rn(0.f);
        int nb = n4 >> 2;
        int t4 = 0;
        for (; t4 + 2 <= nb; t4 += 2) {
            uint32_t p0 = pl[(t4 << 2)];
            uint32_t p1 = pl[(t4 << 2) + 4];
            PROC(p0); PROC(p1);
        }
        if (t4 < nb) { uint32_t p = pl[(t4 << 2)]; PROC(p); }
        // cross-group reduce: lanes l, l+16, l+32, l+48 hold partials of same rows
        int a01 = *(int*)&acc01, a23 = *(int*)&acc23;
        int r01 = __shfl_xor(a01, 16, 64);
        int r23 = __shfl_xor(a23, 16, 64);
        acc01 = __hadd2(acc01, *(__half2*)&r01);
        acc23 = __hadd2(acc23, *(__half2*)&r23);
        a01 = *(int*)&acc01; a23 = *(int*)&acc23;
        r01 = __shfl_xor(a01, 32, 64);
        r23 = __shfl_xor(a23, 32, 64);
        acc01 = __hadd2(acc01, *(__half2*)&r01);
        acc23 = __hadd2(acc23, *(__half2*)&r23);
        float2 f01 = __half22float2(acc01);
        float2 f23 = __half22float2(acc23);
        float v = (g4 & 2) ? ((g4 & 1) ? f23.y : f23.x)
                           : ((g4 & 1) ? f01.y : f01.x);
        orow[d] = v;
    }
}

// ================= launch =================

extern "C" void kernel_launch(void* const* d_in, const int* in_sizes, int n_in,
                              void* d_out, int out_size, void* d_ws, size_t ws_size,
                              hipStream_t stream) {
    const float* b1 = (const float*)d_in[0];
    const float* b2 = (const float*)d_in[1];
    const int*   h1 = (const int*)d_in[2];
    const float* s1 = (const float*)d_in[3];
    const int*   h2 = (const int*)d_in[4];
    const float* s2 = (const float*)d_in[5];
    float* out = (float*)d_out;

    int* cnt2    = (int*)d_ws;            // 8192
    int* boff    = cnt2 + 8192;           // 8192
    int* bucket2 = boff + 8192;           // 512
    int* cnt     = bucket2 + 512;         // 8192
    uint32_t* pairs = (uint32_t*)(cnt + 8192 + 8);   // 8192*NCAP = 589824 u32 (~2.36 MB)

    pA_buckets<<<1, 512, 0, stream>>>(h2, cnt2, boff, bucket2);
    pB_fill   <<<64, 128, 0, stream>>>(h1, cnt2, boff, bucket2, cnt, pairs);

    dim3 g(CBP_W * 8 / ROWS, NSPLIT);     // (64, 4)
    k_main<<<g, NTHREADS, 0, stream>>>(b1, b2, s1, s2, cnt, pairs, out);
}

// Round 6
// 289.471 us; speedup vs baseline: 2.1709x; 2.1709x over previous
//
#include <hip/hip_runtime.h>
#include <hip/hip_fp16.h>
#include <stdint.h>

#define CBP_D 8192
#define CBP_C 512
#define CBP_W 512
#define ROWS 64          // rows staged per block; lane covers 4 rows
#define NTHREADS 1024    // 16 waves
#define NSPLIT 4         // 64 row-blocks x 4 = 256 blocks = 1/CU
#define NCAP 72          // fixed pair-list capacity per d (mean 32, +7 sigma)

// LDS layout (bytes): x2 rows 0..512 (513*128, row 512 = zeros), then x1 rows 0..511
#define X1OFF 65664
#define PADW  (512u << 17)   // pad pair word: j=512 (zero row), i=0

// ================= precompute =================

// pA: single block. cnt2 (histogram of h2), boff (exclusive scan), bucket2
// (j's grouped by target bucket, deterministic order via rank).
__global__ void pA_buckets(const int* __restrict__ h2, int* __restrict__ cnt2_g,
                           int* __restrict__ boff_g, int* __restrict__ bucket2_g) {
    __shared__ int scnt[CBP_D];
    __shared__ int sh2[CBP_C];
    __shared__ int ssum[512];
    int t = threadIdx.x;            // 512 threads
    for (int k = t; k < CBP_D; k += 512) scnt[k] = 0;
    sh2[t] = h2[t];
    __syncthreads();
    atomicAdd(&scnt[sh2[t]], 1);    // counts order-independent -> deterministic
    __syncthreads();
    int base = t * 16;
    int loc[16]; int s = 0;
#pragma unroll
    for (int k = 0; k < 16; ++k) { loc[k] = scnt[base + k]; cnt2_g[base + k] = loc[k]; s += loc[k]; }
    ssum[t] = s;
    __syncthreads();
    int acc = s;
    for (int off = 1; off < 512; off <<= 1) {
        int add = (t >= off) ? ssum[t - off] : 0;
        __syncthreads();
        acc += add; ssum[t] = acc;
        __syncthreads();
    }
    int excl = acc - s;
#pragma unroll
    for (int k = 0; k < 16; ++k) { boff_g[base + k] = excl; scnt[base + k] = excl; excl += loc[k]; }
    __syncthreads();
    int h = sh2[t]; int r = 0;
    for (int j2 = 0; j2 < t; ++j2) r += (sh2[j2] == h);
    bucket2_g[scnt[h] + r] = t;
}

// pB: per-d pair lists at fixed stride NCAP; every quad (4 consecutive d)
// padded to a common multiple-of-4 count with PADW; count in cnt[d].
__global__ void pB_fill(const int* __restrict__ h1, const int* __restrict__ cnt2,
                        const int* __restrict__ boff, const int* __restrict__ bucket2,
                        int* __restrict__ cnt, uint32_t* __restrict__ pairs) {
    __shared__ int sc[CBP_D];       // 32 KB
    __shared__ int sb[CBP_D];       // 32 KB
    __shared__ short sbk[CBP_C];
    __shared__ int sh1[CBP_C];
    __shared__ int rawc[128];
    int tid = threadIdx.x;          // 128
    for (int k = tid; k < CBP_D; k += 128) { sc[k] = cnt2[k]; sb[k] = boff[k]; }
    for (int k = tid; k < CBP_C; k += 128) { sbk[k] = (short)bucket2[k]; sh1[k] = h1[k]; }
    __syncthreads();
    int d = blockIdx.x * 128 + tid;
    uint32_t* pd = pairs + (size_t)d * NCAP;
    int pos = 0;
    for (int i = 0; i < CBP_C; ++i) {
        int t = (d - sh1[i]) & (CBP_D - 1);
        int n = sc[t];
        if (n) {
            int bo = sb[t];
            uint32_t iw = (uint32_t)(i << 7);
            for (int k = 0; k < n && pos < NCAP; ++k)
                pd[pos++] = iw | ((uint32_t)sbk[bo + k] << 17);
        }
    }
    rawc[tid] = pos;
    __syncthreads();
    int q = tid & ~3;
    int qmax = max(max(rawc[q], rawc[q + 1]), max(rawc[q + 2], rawc[q + 3]));
    qmax = (qmax + 3) & ~3;
    for (; pos < qmax; ++pos) pd[pos] = PADW;
    cnt[d] = qmax;
}

// ================= main =================

// Quarter g (lane>>4) owns d_g = quadbase+g; lane l (lane&15) covers rows 4l..4l+3.
#define PROC(P) { \
    uint32_t p_ = (P); \
    uint32_t aB_ = (p_ & 0x1FF80u) + baseA; \
    uint32_t bB_ = ((p_ >> 10) & 0x1FF80u) | baseB; \
    uint2 ra_ = *(const uint2*)(xsh + aB_); \
    uint2 rb_ = *(const uint2*)(xsh + bB_); \
    a01 = __hfma2(*(const __half2*)&ra_.x, *(const __half2*)&rb_.x, a01); \
    a23 = __hfma2(*(const __half2*)&ra_.y, *(const __half2*)&rb_.y, a23); }

__global__ __launch_bounds__(NTHREADS, 1)
void k_main(const float* __restrict__ b1, const float* __restrict__ b2,
            const float* __restrict__ s1, const float* __restrict__ s2,
            const int* __restrict__ cnt, const uint32_t* __restrict__ pairs,
            float* __restrict__ out) {
    __shared__ __align__(16) char xsh[131200];   // x2 (513 rows incl zero) + x1 (512)
    int bx = blockIdx.x;                   // 0..63 row-block
    int gy = blockIdx.y;                   // 0..3
    int r_base = bx * ROWS;
    int b = r_base >> 9;
    int w0 = r_base & (CBP_W - 1);
    int tid = threadIdx.x;

    // stage sign-folded f16, transposed [c][r]; x2 at 0, x1 at X1OFF
    for (int u = tid; u < CBP_C * 8; u += NTHREADS) {
        int c = u >> 3;
        int r8 = (u & 7) << 3;
        size_t g = ((size_t)(b * CBP_C + c)) * CBP_W + w0 + r8;
        float4 u0 = *(const float4*)(b1 + g), u1 = *(const float4*)(b1 + g + 4);
        float4 v0 = *(const float4*)(b2 + g), v1 = *(const float4*)(b2 + g + 4);
        float sa = s1[c], sb = s2[c];
        union { __half2 h2[4]; uint4 q; } A, Bv;
        A.h2[0] = __floats2half2_rn(u0.x * sa, u0.y * sa);
        A.h2[1] = __floats2half2_rn(u0.z * sa, u0.w * sa);
        A.h2[2] = __floats2half2_rn(u1.x * sa, u1.y * sa);
        A.h2[3] = __floats2half2_rn(u1.z * sa, u1.w * sa);
        Bv.h2[0] = __floats2half2_rn(v0.x * sb, v0.y * sb);
        Bv.h2[1] = __floats2half2_rn(v0.z * sb, v0.w * sb);
        Bv.h2[2] = __floats2half2_rn(v1.x * sb, v1.y * sb);
        Bv.h2[3] = __floats2half2_rn(v1.z * sb, v1.w * sb);
        *(uint4*)(xsh + X1OFF + (c << 7) + (r8 << 1)) = A.q;
        *(uint4*)(xsh + (c << 7) + (r8 << 1)) = Bv.q;
    }
    if (tid < 8) *(uint4*)(xsh + 65536 + tid * 16) = make_uint4(0, 0, 0, 0);
    __syncthreads();

    int wv = tid >> 6;                     // 0..15
    int lane = tid & 63;
    int g4 = lane >> 4;                    // quarter: d within quad
    int l = lane & 15;                     // rows 4l..4l+3
    uint32_t baseA = (uint32_t)(X1OFF + (l << 3));
    uint32_t baseB = (uint32_t)(l << 3);
    int dbase = gy * (CBP_D / NSPLIT) + wv * 128;   // wave owns 128 contiguous d's
    float* orow = out + (size_t)(r_base + (l << 2) + g4) * CBP_D;

    for (int q = 0; q < 32; ++q) {
        int quadbase = dbase + (q << 2);
        int nmax = __builtin_amdgcn_readfirstlane(cnt[quadbase]);  // quad-uniform, mult of 4
        const uint32_t* pl = pairs + (size_t)(quadbase + g4) * NCAP;
        float ac0 = 0.f, ac1 = 0.f, ac2 = 0.f, ac3 = 0.f;
        for (int t0 = 0; t0 < nmax; t0 += 16) {
            __half2 a01 = __floats2half2_rn(0.f, 0.f);
            __half2 a23 = __floats2half2_rn(0.f, 0.f);
            int te = (t0 + 16 < nmax) ? t0 + 16 : nmax;
            for (int t = t0; t < te; t += 4) {
                uint4 pp = *(const uint4*)(pl + t);
                PROC(pp.x); PROC(pp.y); PROC(pp.z); PROC(pp.w);
            }
            float2 u = __half22float2(a01); ac0 += u.x; ac1 += u.y;
            float2 v = __half22float2(a23); ac2 += v.x; ac3 += v.y;
        }
        // 4x4 transpose across quarters: lane ends with row 4l+g4 at d quadbase+0..3
        float f0 = ac0, f1 = ac1, f2 = ac2, f3 = ac3;
        float s0 = __shfl_xor(f0, 16, 64), s1 = __shfl_xor(f1, 16, 64);
        float s2 = __shfl_xor(f2, 16, 64), s3 = __shfl_xor(f3, 16, 64);
        bool ge1 = (g4 & 1) == 0;
        float n0 = ge1 ? f0 : s1, n1 = ge1 ? s0 : f1;
        float n2 = ge1 ? f2 : s3, n3 = ge1 ? s2 : f3;
        s0 = __shfl_xor(n0, 32, 64); s1 = __shfl_xor(n1, 32, 64);
        s2 = __shfl_xor(n2, 32, 64); s3 = __shfl_xor(n3, 32, 64);
        bool ge2 = (g4 & 2) == 0;
        f0 = ge2 ? n0 : s2; f1 = ge2 ? n1 : s3;
        f2 = ge2 ? s0 : n2; f3 = ge2 ? s1 : n3;
        *(float4*)(orow + quadbase) = make_float4(f0, f1, f2, f3);
    }
}

// ================= launch =================

extern "C" void kernel_launch(void* const* d_in, const int* in_sizes, int n_in,
                              void* d_out, int out_size, void* d_ws, size_t ws_size,
                              hipStream_t stream) {
    const float* b1 = (const float*)d_in[0];
    const float* b2 = (const float*)d_in[1];
    const int*   h1 = (const int*)d_in[2];
    const float* s1 = (const float*)d_in[3];
    const int*   h2 = (const int*)d_in[4];
    const float* s2 = (const float*)d_in[5];
    float* out = (float*)d_out;

    int* cnt2    = (int*)d_ws;            // 8192
    int* boff    = cnt2 + 8192;           // 8192
    int* bucket2 = boff + 8192;           // 512
    int* cnt     = bucket2 + 512;         // 8192
    uint32_t* pairs = (uint32_t*)(cnt + 8192 + 8);   // 8192*NCAP u32 (~2.36 MB)

    pA_buckets<<<1, 512, 0, stream>>>(h2, cnt2, boff, bucket2);
    pB_fill   <<<64, 128, 0, stream>>>(h1, cnt2, boff, bucket2, cnt, pairs);

    dim3 g(CBP_W * 8 / ROWS, NSPLIT);     // (64, 4)
    k_main<<<g, NTHREADS, 0, stream>>>(b1, b2, s1, s2, cnt, pairs, out);
}

// Round 7
// 263.918 us; speedup vs baseline: 2.3811x; 1.0968x over previous
//
#include <hip/hip_runtime.h>
#include <hip/hip_fp16.h>
#include <stdint.h>

#define CBP_D 8192
#define CBP_C 512
#define CBP_W 512
#define ROWS 64          // rows staged per block; lane covers 4 rows
#define NTHREADS 1024    // 16 waves
#define NSPLIT 4         // 64 row-blocks x 4 = 256 blocks = 1/CU
#define NCAP 72          // fixed pair-list capacity per d (mean 32, +7 sigma)

// LDS layout (bytes): x2 rows 0..512 (513*128, row 512 = zeros), then x1 rows 0..511
#define X1OFF 65664
#define PADW  (512u << 17)   // pad pair word: j=512 (zero row), i=0

// ================= precompute =================

// pA: single block. cnt2 (histogram of h2), boff (exclusive scan), bucket2
// (j's grouped by target bucket, deterministic order via rank).
__global__ void pA_buckets(const int* __restrict__ h2, int* __restrict__ cnt2_g,
                           int* __restrict__ boff_g, int* __restrict__ bucket2_g) {
    __shared__ int scnt[CBP_D];
    __shared__ int sh2[CBP_C];
    __shared__ int ssum[512];
    int t = threadIdx.x;            // 512 threads
    for (int k = t; k < CBP_D; k += 512) scnt[k] = 0;
    sh2[t] = h2[t];
    __syncthreads();
    atomicAdd(&scnt[sh2[t]], 1);    // counts order-independent -> deterministic
    __syncthreads();
    int base = t * 16;
    int loc[16]; int s = 0;
#pragma unroll
    for (int k = 0; k < 16; ++k) { loc[k] = scnt[base + k]; cnt2_g[base + k] = loc[k]; s += loc[k]; }
    ssum[t] = s;
    __syncthreads();
    int acc = s;
    for (int off = 1; off < 512; off <<= 1) {
        int add = (t >= off) ? ssum[t - off] : 0;
        __syncthreads();
        acc += add; ssum[t] = acc;
        __syncthreads();
    }
    int excl = acc - s;
#pragma unroll
    for (int k = 0; k < 16; ++k) { boff_g[base + k] = excl; scnt[base + k] = excl; excl += loc[k]; }
    __syncthreads();
    int h = sh2[t]; int r = 0;
    for (int j2 = 0; j2 < t; ++j2) r += (sh2[j2] == h);
    bucket2_g[scnt[h] + r] = t;
}

// pB: per-d pair lists at fixed stride NCAP; every quad (4 consecutive d)
// padded to a common multiple-of-4 count with PADW; count in cnt[d].
__global__ void pB_fill(const int* __restrict__ h1, const int* __restrict__ cnt2,
                        const int* __restrict__ boff, const int* __restrict__ bucket2,
                        int* __restrict__ cnt, uint32_t* __restrict__ pairs) {
    __shared__ int sc[CBP_D];       // 32 KB
    __shared__ int sb[CBP_D];       // 32 KB
    __shared__ short sbk[CBP_C];
    __shared__ int sh1[CBP_C];
    __shared__ int rawc[128];
    int tid = threadIdx.x;          // 128
    for (int k = tid; k < CBP_D; k += 128) { sc[k] = cnt2[k]; sb[k] = boff[k]; }
    for (int k = tid; k < CBP_C; k += 128) { sbk[k] = (short)bucket2[k]; sh1[k] = h1[k]; }
    __syncthreads();
    int d = blockIdx.x * 128 + tid;
    uint32_t* pd = pairs + (size_t)d * NCAP;
    int pos = 0;
    for (int i = 0; i < CBP_C; ++i) {
        int t = (d - sh1[i]) & (CBP_D - 1);
        int n = sc[t];
        if (n) {
            int bo = sb[t];
            uint32_t iw = (uint32_t)(i << 7);
            for (int k = 0; k < n && pos < NCAP; ++k)
                pd[pos++] = iw | ((uint32_t)sbk[bo + k] << 17);
        }
    }
    rawc[tid] = pos;
    __syncthreads();
    int q = tid & ~3;
    int qmax = max(max(rawc[q], rawc[q + 1]), max(rawc[q + 2], rawc[q + 3]));
    qmax = (qmax + 3) & ~3;
    for (; pos < qmax; ++pos) pd[pos] = PADW;
    cnt[d] = qmax;
}

// ================= main =================

// Quarter g (lane>>4) owns d = quadbase+g; lane l (lane&15) covers rows 4l..4l+3.
#define PROC(P) { \
    uint32_t p_ = (P); \
    uint32_t aB_ = (p_ & 0x1FF80u) + baseA; \
    uint32_t bB_ = ((p_ >> 10) & 0x1FF80u) | baseB; \
    uint2 ra_ = *(const uint2*)(xsh + aB_); \
    uint2 rb_ = *(const uint2*)(xsh + bB_); \
    a01 = __hfma2(*(const __half2*)&ra_.x, *(const __half2*)&rb_.x, a01); \
    a23 = __hfma2(*(const __half2*)&ra_.y, *(const __half2*)&rb_.y, a23); }

// Process one quad (4 consecutive d); result float4 (this lane's row, 4 d) in DEST.
// Maintains the cross-quad pipeline regs nmax_cur/pp_cur.
#define QUAD(K, DEST) { \
    int q_ = (qq << 2) + (K); \
    int quadbase_ = dbase + (q_ << 2); \
    int nmax_ = nmax_cur; \
    uint4 cur_ = pp_cur; \
    int nq_ = (q_ + 1 < 32) ? q_ + 1 : 31; \
    int nmax_n_ = __builtin_amdgcn_readfirstlane(cnt[dbase + (nq_ << 2)]); \
    uint4 pp_n_ = *(const uint4*)(pairs + (size_t)(dbase + (nq_ << 2) + g4) * NCAP); \
    const uint4* pl4_ = (const uint4*)(pairs + (size_t)(quadbase_ + g4) * NCAP); \
    float ac0 = 0.f, ac1 = 0.f, ac2 = 0.f, ac3 = 0.f; \
    int nb_ = nmax_ >> 2; \
    int t4_ = 0; \
    while (t4_ < nb_) { \
        __half2 a01 = __floats2half2_rn(0.f, 0.f); \
        __half2 a23 = __floats2half2_rn(0.f, 0.f); \
        int ce_ = (t4_ + 4 < nb_) ? t4_ + 4 : nb_; \
        for (; t4_ < ce_; ++t4_) { \
            uint4 c_ = cur_; \
            int nxt_ = (t4_ + 1 < nb_) ? t4_ + 1 : t4_; \
            cur_ = pl4_[nxt_]; \
            PROC(c_.x); PROC(c_.y); PROC(c_.z); PROC(c_.w); \
        } \
        float2 u_ = __half22float2(a01); ac0 += u_.x; ac1 += u_.y; \
        float2 v_ = __half22float2(a23); ac2 += v_.x; ac3 += v_.y; \
    } \
    nmax_cur = nmax_n_; pp_cur = pp_n_; \
    float s0_ = __shfl_xor(ac0, 16, 64), s1_ = __shfl_xor(ac1, 16, 64); \
    float s2_ = __shfl_xor(ac2, 16, 64), s3_ = __shfl_xor(ac3, 16, 64); \
    bool ge1_ = (g4 & 1) == 0; \
    float n0_ = ge1_ ? ac0 : s1_, n1_ = ge1_ ? s0_ : ac1; \
    float n2_ = ge1_ ? ac2 : s3_, n3_ = ge1_ ? s2_ : ac3; \
    s0_ = __shfl_xor(n0_, 32, 64); s1_ = __shfl_xor(n1_, 32, 64); \
    s2_ = __shfl_xor(n2_, 32, 64); s3_ = __shfl_xor(n3_, 32, 64); \
    bool ge2_ = (g4 & 2) == 0; \
    DEST = make_float4(ge2_ ? n0_ : s2_, ge2_ ? n1_ : s3_, \
                       ge2_ ? s0_ : n2_, ge2_ ? s1_ : n3_); }

__global__ __launch_bounds__(NTHREADS, 4)
void k_main(const float* __restrict__ b1, const float* __restrict__ b2,
            const float* __restrict__ s1, const float* __restrict__ s2,
            const int* __restrict__ cnt, const uint32_t* __restrict__ pairs,
            float* __restrict__ out) {
    __shared__ __align__(16) char xsh[131200];   // x2 (513 rows incl zero) + x1 (512)
    int bx = blockIdx.x;                   // 0..63 row-block
    int gy = blockIdx.y;                   // 0..3
    int r_base = bx * ROWS;
    int b = r_base >> 9;
    int w0 = r_base & (CBP_W - 1);
    int tid = threadIdx.x;

    // stage sign-folded f16, transposed [c][r]; x2 at 0, x1 at X1OFF
    for (int u = tid; u < CBP_C * 8; u += NTHREADS) {
        int c = u >> 3;
        int r8 = (u & 7) << 3;
        size_t g = ((size_t)(b * CBP_C + c)) * CBP_W + w0 + r8;
        float4 u0 = *(const float4*)(b1 + g), u1 = *(const float4*)(b1 + g + 4);
        float4 v0 = *(const float4*)(b2 + g), v1 = *(const float4*)(b2 + g + 4);
        float sa = s1[c], sb = s2[c];
        union { __half2 h2[4]; uint4 q; } A, Bv;
        A.h2[0] = __floats2half2_rn(u0.x * sa, u0.y * sa);
        A.h2[1] = __floats2half2_rn(u0.z * sa, u0.w * sa);
        A.h2[2] = __floats2half2_rn(u1.x * sa, u1.y * sa);
        A.h2[3] = __floats2half2_rn(u1.z * sa, u1.w * sa);
        Bv.h2[0] = __floats2half2_rn(v0.x * sb, v0.y * sb);
        Bv.h2[1] = __floats2half2_rn(v0.z * sb, v0.w * sb);
        Bv.h2[2] = __floats2half2_rn(v1.x * sb, v1.y * sb);
        Bv.h2[3] = __floats2half2_rn(v1.z * sb, v1.w * sb);
        *(uint4*)(xsh + X1OFF + (c << 7) + (r8 << 1)) = A.q;
        *(uint4*)(xsh + (c << 7) + (r8 << 1)) = Bv.q;
    }
    if (tid < 8) *(uint4*)(xsh + 65536 + tid * 16) = make_uint4(0, 0, 0, 0);
    __syncthreads();

    int wv = tid >> 6;                     // 0..15
    int lane = tid & 63;
    int g4 = lane >> 4;                    // quarter: d within quad
    int l = lane & 15;                     // rows 4l..4l+3
    uint32_t baseA = (uint32_t)(X1OFF + (l << 3));
    uint32_t baseB = (uint32_t)(l << 3);
    int dbase = gy * (CBP_D / NSPLIT) + wv * 128;   // wave owns 128 contiguous d's

    // cross-quad pipeline: preloaded count + first uint4 of the upcoming quad
    int nmax_cur = __builtin_amdgcn_readfirstlane(cnt[dbase]);
    uint4 pp_cur = *(const uint4*)(pairs + (size_t)(dbase + g4) * NCAP);

    // lane stores row r_base + 4l + g4, 16 consecutive d (64 B) per burst
    float* obase = out + (size_t)(r_base + (l << 2) + g4) * CBP_D + dbase;

    for (int qq = 0; qq < 8; ++qq) {
        float4 B0, B1, B2, B3;
        QUAD(0, B0); QUAD(1, B1); QUAD(2, B2); QUAD(3, B3);
        float* o_ = obase + (qq << 4);
        *(float4*)(o_)      = B0;
        *(float4*)(o_ + 4)  = B1;
        *(float4*)(o_ + 8)  = B2;
        *(float4*)(o_ + 12) = B3;
    }
}

// ================= launch =================

extern "C" void kernel_launch(void* const* d_in, const int* in_sizes, int n_in,
                              void* d_out, int out_size, void* d_ws, size_t ws_size,
                              hipStream_t stream) {
    const float* b1 = (const float*)d_in[0];
    const float* b2 = (const float*)d_in[1];
    const int*   h1 = (const int*)d_in[2];
    const float* s1 = (const float*)d_in[3];
    const int*   h2 = (const int*)d_in[4];
    const float* s2 = (const float*)d_in[5];
    float* out = (float*)d_out;

    int* cnt2    = (int*)d_ws;            // 8192
    int* boff    = cnt2 + 8192;           // 8192
    int* bucket2 = boff + 8192;           // 512
    int* cnt     = bucket2 + 512;         // 8192
    uint32_t* pairs = (uint32_t*)(cnt + 8192 + 8);   // 8192*NCAP u32 (~2.36 MB)

    pA_buckets<<<1, 512, 0, stream>>>(h2, cnt2, boff, bucket2);
    pB_fill   <<<64, 128, 0, stream>>>(h1, cnt2, boff, bucket2, cnt, pairs);

    dim3 g(CBP_W * 8 / ROWS, NSPLIT);     // (64, 4)
    k_main<<<g, NTHREADS, 0, stream>>>(b1, b2, s1, s2, cnt, pairs, out);
}